// Round 7
// baseline (180.091 us; speedup 1.0000x reference)
//
#include <hip/hip_runtime.h>

// ---------------------------------------------------------------------------
// Attention block, faithful to reference quirks:
//  - raw reshape head split: per (b,h) Q/K/V are contiguous [2048,64] slabs
//  - softmax over QUERY axis: attn[q,k] = exp(s[q,k]) / sum_q exp(s[q,k])
// Algebra: Z[k] = sum_q exp(s); fold 1/Z into V (Vn = V/Z); out = exp(S)@Vn.
// attn main loop is barrier-free: Q,K,V all read direct from L2 (working set
// per XCD ~3MB < 4MB L2); LDS only for epilogue cross-wave reduction.
// Numerics: round-5-proven path (__expf, bfpack, 0.125 Q scale).
// ---------------------------------------------------------------------------

typedef unsigned short ush;
typedef short s16v8 __attribute__((ext_vector_type(8)));
typedef float f32x4 __attribute__((ext_vector_type(4)));

#define BATCH_STRIDE 1048576   // T*D = 2048*512
#define HEAD_STRIDE  131072    // T*hd = 2048*64

__device__ __forceinline__ ush f2bf(float f) {
  unsigned int u = __builtin_bit_cast(unsigned int, f);
  u = (u + 0x7FFFu + ((u >> 16) & 1u)) >> 16;   // round-to-nearest-even
  return (ush)u;
}
__device__ __forceinline__ float bf2f(ush u) {
  return __builtin_bit_cast(float, (unsigned int)u << 16);
}
// fast pack two f32 -> 2xbf16 u32 (round-half-up; P is positive & well-scaled)
__device__ __forceinline__ unsigned int bfpack(float lo, float hi) {
  unsigned int ul = __builtin_bit_cast(unsigned int, lo) + 0x8000u;
  unsigned int uh = __builtin_bit_cast(unsigned int, hi) + 0x8000u;
  return (uh & 0xFFFF0000u) | (ul >> 16);
}

// swizzled LDS tile (8-chunk rows): 16B chunk at slot = row*8 + (ch ^ (row&7))
__device__ __forceinline__ s16v8 ldsfrag(const ush* base, int row, int ch) {
  return *(const s16v8*)(base + (((row) << 3) + ((ch) ^ ((row) & 7))) * 8);
}

__device__ __forceinline__ f32x4 mfma16(s16v8 a, s16v8 b, f32x4 c) {
  return __builtin_amdgcn_mfma_f32_16x16x32_bf16(a, b, c, 0, 0, 0);
}

__device__ __forceinline__ void gll16(const ush* g, ush* l) {
  __builtin_amdgcn_global_load_lds(
      (const __attribute__((address_space(1))) void*)g,
      (__attribute__((address_space(3))) void*)l, 16, 0, 0);
}

// ---------------------------------------------------------------------------
// f32 -> bf16 for X and the 4 weight matrices
// ---------------------------------------------------------------------------
__global__ __launch_bounds__(256) void k_convert(
    const float* __restrict__ X, const float* __restrict__ Wq,
    const float* __restrict__ Wk, const float* __restrict__ Wv,
    const float* __restrict__ Wo, ush* __restrict__ Xb, ush* __restrict__ Wb) {
  int id = blockIdx.x * 256 + threadIdx.x;
  const float* src;
  ush* dst;
  int idx;
  if (id < 1048576) {
    src = X; dst = Xb; idx = id;
  } else {
    int t = id - 1048576;
    int w = t >> 16;
    idx = t & 65535;
    src = (w == 0) ? Wq : (w == 1) ? Wk : (w == 2) ? Wv : Wo;
    dst = Wb + w * 262144;
  }
  float4 v = ((const float4*)src)[idx];
  ushort4 o;
  o.x = f2bf(v.x); o.y = f2bf(v.y); o.z = f2bf(v.z); o.w = f2bf(v.w);
  ((ushort4*)dst)[idx] = o;
}

// ---------------------------------------------------------------------------
// 2-phase dbuf GEMM, BM=128 BN=128 BK=64 (verified round 2)
// ---------------------------------------------------------------------------
__device__ __forceinline__ void stage_tile(
    const ush* __restrict__ A, const ush* __restrict__ W,
    ush* lds, int m0, int n0, int k0, int wid, int lane) {
#pragma unroll
  for (int i = 0; i < 4; i++) {
    int s = wid * 4 + i;
    int row = s * 8 + (lane >> 3);
    int ch = (lane & 7) ^ (lane >> 3);
    gll16(A + (size_t)(m0 + row) * 512 + k0 + ch * 8, lds + s * 512);
    gll16(W + (size_t)(n0 + row) * 512 + k0 + ch * 8, lds + 8192 + s * 512);
  }
}

template <int OUTMODE>
__device__ __forceinline__ void gemm2(
    const ush* __restrict__ A, const ush* __restrict__ W,
    ush* __restrict__ Obf, float* __restrict__ Ofp,
    const float* __restrict__ bias, int m0, int n0) {
  __shared__ __align__(16) ush SM[2][16384];
  const int tid = threadIdx.x, lane = tid & 63, wid = tid >> 6;
  const int l16 = lane & 15, lg = lane >> 4;
  const int wr = wid >> 1, wc = wid & 1;

  const f32x4 z4 = {0.f, 0.f, 0.f, 0.f};
  f32x4 acc[4][4];
#pragma unroll
  for (int i = 0; i < 4; i++)
#pragma unroll
    for (int j = 0; j < 4; j++) acc[i][j] = z4;

  stage_tile(A, W, &SM[0][0], m0, n0, 0, wid, lane);
  __syncthreads();
  int cur = 0;
#pragma unroll 1
  for (int t = 0; t < 8; t++) {
    if (t < 7) stage_tile(A, W, &SM[cur ^ 1][0], m0, n0, (t + 1) * 64, wid, lane);
    const ush* At = &SM[cur][0];
    const ush* Bt = &SM[cur][8192];
    s16v8 af[4][2], bf2[4][2];
#pragma unroll
    for (int ms = 0; ms < 4; ms++)
#pragma unroll
      for (int ks = 0; ks < 2; ks++)
        af[ms][ks] = ldsfrag(At, wr * 64 + ms * 16 + l16, ks * 4 + lg);
#pragma unroll
    for (int ns = 0; ns < 4; ns++)
#pragma unroll
      for (int ks = 0; ks < 2; ks++)
        bf2[ns][ks] = ldsfrag(Bt, wc * 64 + ns * 16 + l16, ks * 4 + lg);
#pragma unroll
    for (int ms = 0; ms < 4; ms++)
#pragma unroll
      for (int ns = 0; ns < 4; ns++)
#pragma unroll
        for (int ks = 0; ks < 2; ks++)
          acc[ms][ns] = mfma16(af[ms][ks], bf2[ns][ks], acc[ms][ns]);
    __syncthreads();
    cur ^= 1;
  }

  if (OUTMODE == 0) {
    const int gc0 = n0 + wc * 64;
    const float alpha = (gc0 < 512) ? 0.125f : 1.0f;
    ush* cw = &SM[0][0] + wid * 4096;
#pragma unroll
    for (int ms = 0; ms < 4; ms++)
#pragma unroll
      for (int ns = 0; ns < 4; ns++)
#pragma unroll
        for (int r = 0; r < 4; r++) {
          int row = ms * 16 + lg * 4 + r;
          int col = ns * 16 + l16;
          int sw = (((col >> 3) ^ (row & 7)) << 3) + (col & 7);
          cw[row * 64 + sw] = f2bf(acc[ms][ns][r] * alpha);
        }
    __syncthreads();
    const int z = gc0 >> 9, jl = gc0 & 511;
    ush* og = Obf + (size_t)z * 4194304 + (size_t)(m0 + wr * 64) * 512 + jl;
#pragma unroll
    for (int i = 0; i < 8; i++) {
      int row = i * 8 + (lane >> 3), ch = lane & 7;
      s16v8 v = ldsfrag(cw, row, ch);
      *(s16v8*)(og + (size_t)row * 512 + ch * 8) = v;
    }
  } else {
#pragma unroll
    for (int ms = 0; ms < 4; ms++)
#pragma unroll
      for (int ns = 0; ns < 4; ns++) {
        int gcol = n0 + wc * 64 + ns * 16 + l16;
#pragma unroll
        for (int r = 0; r < 4; r++) {
          int grow = m0 + wr * 64 + ms * 16 + lg * 4 + r;
          Ofp[(size_t)grow * 512 + gcol] = acc[ms][ns][r] + bias[gcol];
        }
      }
  }
}

__global__ __launch_bounds__(256) void k_gemm_qkv(
    const ush* __restrict__ Xb, const ush* __restrict__ Wb,
    ush* __restrict__ QKV) {
  gemm2<0>(Xb, Wb, QKV, nullptr, nullptr, blockIdx.x * 128, blockIdx.y * 128);
}

__global__ __launch_bounds__(256) void k_gemm_out(
    const ush* __restrict__ AO, const ush* __restrict__ Wob,
    float* __restrict__ out, const float* __restrict__ bias) {
  gemm2<1>(AO, Wob, nullptr, out, bias, blockIdx.x * 128, blockIdx.y * 128);
}

// ---------------------------------------------------------------------------
// k_colv: per (kt: 64 k-rows, bh): Z[k] = sum_q exp(s[q,k]) via swapped-QK
// (K rows as A-operand in regs; Q direct-global), then Vn = V/Z written
// transposed: Vst[d][2048 k].
// ---------------------------------------------------------------------------
__global__ __launch_bounds__(256) void k_colv(
    const ush* __restrict__ Qb, const ush* __restrict__ Kb,
    const ush* __restrict__ Vb, ush* __restrict__ Vst) {
  const int wg = blockIdx.x;
  const int xcd = wg & 7, slot = wg >> 3;
  const int bh = xcd * 4 + (slot >> 5), kt = slot & 31;
  const int b = bh >> 3, h = bh & 7;
  const size_t base = (size_t)b * BATCH_STRIDE + h * HEAD_STRIDE;
  const ush* Qg = Qb + base;
  const ush* Kg = Kb + base + kt * 4096;
  const ush* Vg = Vb + base + kt * 4096;
  ush* dst = Vst + base + kt * 64;

  __shared__ float Zp[256];
  __shared__ float invZ[64];
  __shared__ __align__(16) ush L[64][72];

  const int tid = threadIdx.x, lane = tid & 63, wid = tid >> 6;
  const int l16 = lane & 15, lg = lane >> 4;

  // V tile loaded early (latency hidden under the Z pass)
  const int cid0 = tid * 2, cid1 = tid * 2 + 1;
  uint4 vr0 = *(const uint4*)(Vg + (size_t)(cid0 >> 3) * 64 + (cid0 & 7) * 8);
  uint4 vr1 = *(const uint4*)(Vg + (size_t)(cid1 >> 3) * 64 + (cid1 & 7) * 8);

  // K fragments (A-operand): rows kc*16+l16, hd = ks*32 + lg*8..+7
  s16v8 kf[4][2];
#pragma unroll
  for (int kc = 0; kc < 4; kc++)
#pragma unroll
    for (int ks = 0; ks < 2; ks++)
      kf[kc][ks] = *(const s16v8*)(Kg + (size_t)(kc * 16 + l16) * 64 + ks * 32 + lg * 8);

  const f32x4 z4 = {0.f, 0.f, 0.f, 0.f};
  f32x4 zacc[4];
#pragma unroll
  for (int kc = 0; kc < 4; kc++) zacc[kc] = z4;

#pragma unroll 1
  for (int t = 0; t < 8; t++) {
    size_t q0 = (size_t)(t * 4 + wid) * 64;
#pragma unroll
    for (int ms = 0; ms < 4; ms++) {
      const ush* qrow = Qg + (q0 + ms * 16 + l16) * 64;
      s16v8 qf0 = *(const s16v8*)(qrow + lg * 8);
      s16v8 qf1 = *(const s16v8*)(qrow + 32 + lg * 8);
#pragma unroll
      for (int kc = 0; kc < 4; kc++) {
        f32x4 s = mfma16(kf[kc][0], qf0, z4);
        s = mfma16(kf[kc][1], qf1, s);
#pragma unroll
        for (int r = 0; r < 4; r++) zacc[kc][r] += __expf(s[r]);
      }
    }
  }

  // write V tile to LDS (plain, padded) while reducing Z
  *(uint4*)(&L[cid0 >> 3][(cid0 & 7) * 8]) = vr0;
  *(uint4*)(&L[cid1 >> 3][(cid1 & 7) * 8]) = vr1;

#pragma unroll
  for (int kc = 0; kc < 4; kc++)
#pragma unroll
    for (int r = 0; r < 4; r++) {
      float v = zacc[kc][r];
      v += __shfl_xor(v, 1); v += __shfl_xor(v, 2);
      v += __shfl_xor(v, 4); v += __shfl_xor(v, 8);
      if (l16 == 0) Zp[wid * 64 + kc * 16 + lg * 4 + r] = v;
    }
  __syncthreads();
  if (tid < 64)
    invZ[tid] = 1.0f / (Zp[tid] + Zp[64 + tid] + Zp[128 + tid] + Zp[192 + tid]);
  __syncthreads();

  // transpose + scale: Vn^T[d][k]
#pragma unroll
  for (int c = 0; c < 2; c++) {
    int cid = tid * 2 + c, d = cid >> 3, ch = cid & 7;
    float4 iz0 = *(const float4*)(invZ + ch * 8);
    float4 iz1 = *(const float4*)(invZ + ch * 8 + 4);
    ush tmp[8];
#pragma unroll
    for (int j = 0; j < 4; j++) tmp[j] = f2bf(bf2f(L[ch * 8 + j][d]) * iz0[j]);
#pragma unroll
    for (int j = 0; j < 4; j++) tmp[4 + j] = f2bf(bf2f(L[ch * 8 + 4 + j][d]) * iz1[j]);
    *(uint4*)(dst + (size_t)d * 2048 + ch * 8) = *(const uint4*)tmp;
  }
}

// ---------------------------------------------------------------------------
// k_attn: out[q,d] = sum_k exp(s[q,k]) * Vn[k,d]
// Block: 64 q rows; 4 waves each own a 16-k slice of each 64-k tile; two
// tiles paired per iter (128 k) to fill K=32 MFMA fragments.
// Swapped QK (A=K) => lane holds P[q=l16][k=lg*4+r]: exact A-frag layout.
// Q,K,Vn ALL direct from global (L2-resident) -> no barriers in main loop.
// LDS only for epilogue cross-wave reduction (slot-major, conflict-free).
// ---------------------------------------------------------------------------
__global__ __launch_bounds__(256) void k_attn(
    const ush* __restrict__ Qb, const ush* __restrict__ Kb,
    const ush* __restrict__ Vst, ush* __restrict__ AO) {
  const int wg = blockIdx.x;
  const int xcd = wg & 7, slot = wg >> 3;
  const int bh = xcd * 4 + (slot >> 5), qb = slot & 31;
  const int b = bh >> 3, h = bh & 7;
  const size_t base = (size_t)b * BATCH_STRIDE + h * HEAD_STRIDE;
  const ush* Qg = Qb + base + qb * 4096;   // 64 q rows x 64 dims
  const ush* Kg = Kb + base;
  const ush* Vg = Vst + base;              // [64 d][2048 k]
  ush* aog = AO + base + qb * 4096;

  __shared__ __align__(16) char smraw[32768];  // epilogue only: 2 x 16KB

  const int tid = threadIdx.x, lane = tid & 63, wid = tid >> 6;
  const int l16 = lane & 15, lg = lane >> 4;

  // Q fragments direct from global (held whole kernel)
  s16v8 qa[4][2];
#pragma unroll
  for (int ms = 0; ms < 4; ms++)
#pragma unroll
    for (int ks = 0; ks < 2; ks++)
      qa[ms][ks] = *(const s16v8*)(Qg + (size_t)(ms * 16 + l16) * 64 + ks * 32 + lg * 8);

  const f32x4 z4 = {0.f, 0.f, 0.f, 0.f};
  f32x4 oacc[4][4];
#pragma unroll
  for (int i = 0; i < 4; i++)
#pragma unroll
    for (int j = 0; j < 4; j++) oacc[i][j] = z4;

  const ush* krow = Kg + (size_t)(wid * 16 + l16) * 64;

#pragma unroll 2
  for (int tp = 0; tp < 16; tp++) {
    // K fragments for both tiles of the pair (direct global, L2)
    const ush* kr = krow + (size_t)tp * 8192;
    s16v8 kf0[2], kf1[2];
    kf0[0] = *(const s16v8*)(kr + lg * 8);
    kf0[1] = *(const s16v8*)(kr + 32 + lg * 8);
    kf1[0] = *(const s16v8*)(kr + 4096 + lg * 8);
    kf1[1] = *(const s16v8*)(kr + 4096 + 32 + lg * 8);

    // Vn B-fragments direct from global: per dt, 4 k from each tile half
    uint4 vbu[4];
#pragma unroll
    for (int dt = 0; dt < 4; dt++) {
      const ush* vp =
          Vg + (size_t)(dt * 16 + l16) * 2048 + tp * 128 + wid * 16 + lg * 4;
      uint2 a = *(const uint2*)vp;
      uint2 bq = *(const uint2*)(vp + 64);
      vbu[dt].x = a.x; vbu[dt].y = a.y; vbu[dt].z = bq.x; vbu[dt].w = bq.y;
    }

#pragma unroll
    for (int ms = 0; ms < 4; ms++) {
      f32x4 sA = mfma16(kf0[0], qa[ms][0], z4);
      sA = mfma16(kf0[1], qa[ms][1], sA);
      f32x4 sB = mfma16(kf1[0], qa[ms][0], z4);
      sB = mfma16(kf1[1], qa[ms][1], sB);
      uint4 pu;
      pu.x = bfpack(__expf(sA[0]), __expf(sA[1]));
      pu.y = bfpack(__expf(sA[2]), __expf(sA[3]));
      pu.z = bfpack(__expf(sB[0]), __expf(sB[1]));
      pu.w = bfpack(__expf(sB[2]), __expf(sB[3]));
      s16v8 pa = __builtin_bit_cast(s16v8, pu);
#pragma unroll
      for (int dt = 0; dt < 4; dt++)
        oacc[ms][dt] = mfma16(pa, __builtin_bit_cast(s16v8, vbu[dt]), oacc[ms][dt]);
    }
  }

  // ---- cross-wave k-slice reduction: slot-major, conflict-free ----
  // region r (0/1): 16 slots x 64 lanes x f32x4 = 16KB
  float* red = (float*)smraw;
  if (wid >= 2) {
    float* rg = red + (wid - 2) * 4096;
#pragma unroll
    for (int ms = 0; ms < 4; ms++)
#pragma unroll
      for (int dt = 0; dt < 4; dt++)
        *(f32x4*)(rg + (ms * 4 + dt) * 256 + lane * 4) = oacc[ms][dt];
  }
  __syncthreads();
  if (wid < 2) {
    float* rg = red + wid * 4096;
#pragma unroll
    for (int ms = 0; ms < 4; ms++)
#pragma unroll
      for (int dt = 0; dt < 4; dt++)
        oacc[ms][dt] += *(const f32x4*)(rg + (ms * 4 + dt) * 256 + lane * 4);
  }
  __syncthreads();
  if (wid == 1) {
#pragma unroll
    for (int ms = 0; ms < 4; ms++)
#pragma unroll
      for (int dt = 0; dt < 4; dt++)
        *(f32x4*)(red + (ms * 4 + dt) * 256 + lane * 4) = oacc[ms][dt];
  }
  __syncthreads();
  if (wid == 0) {
#pragma unroll
    for (int ms = 0; ms < 4; ms++)
#pragma unroll
      for (int dt = 0; dt < 4; dt++)
        oacc[ms][dt] += *(const f32x4*)(red + (ms * 4 + dt) * 256 + lane * 4);
  }
  __syncthreads();   // all reads done before out-tile overwrites region 0
  ush* ot = (ush*)smraw;   // 64x64 bf16 out tile
  if (wid == 0) {
#pragma unroll
    for (int ms = 0; ms < 4; ms++)
#pragma unroll
      for (int dt = 0; dt < 4; dt++)
#pragma unroll
        for (int r = 0; r < 4; r++)
          ot[(ms * 16 + lg * 4 + r) * 64 + dt * 16 + l16] = f2bf(oacc[ms][dt][r]);
  }
  __syncthreads();
#pragma unroll
  for (int rd = 0; rd < 2; rd++) {
    int id = rd * 256 + tid;
    *(s16v8*)(aog + id * 8) = *(const s16v8*)(ot + id * 8);
  }
}

// ---------------------------------------------------------------------------
extern "C" void kernel_launch(void* const* d_in, const int* in_sizes, int n_in,
                              void* d_out, int out_size, void* d_ws, size_t ws_size,
                              hipStream_t stream) {
  const float* X  = (const float*)d_in[0];
  const float* Wq = (const float*)d_in[1];
  const float* Wk = (const float*)d_in[2];
  const float* Wv = (const float*)d_in[3];
  const float* Wo = (const float*)d_in[4];
  const float* bo = (const float*)d_in[5];

  ush* Qb  = (ush*)d_ws;          // QKV contiguous: 3 x 4M bf16
  ush* Kb  = Qb + 4194304;
  ush* Vb  = Kb + 4194304;
  ush* Vst = Vb + 4194304;        // Vn transposed [d][k] per head
  ush* AO  = Vst + 4194304;
  ush* Xb  = AO + 4194304;
  ush* Wb  = Xb + 4194304;        // 4 x 262144 (Wq,Wk,Wv,Wo)

  k_convert<<<5120, 256, 0, stream>>>(X, Wq, Wk, Wv, Wo, Xb, Wb);
  k_gemm_qkv<<<dim3(64, 12), 256, 0, stream>>>(Xb, Wb, Qb);
  k_colv<<<1024, 256, 0, stream>>>(Qb, Kb, Vb, Vst);
  k_attn<<<1024, 256, 0, stream>>>(Qb, Kb, Vst, AO);
  k_gemm_out<<<dim3(64, 4), 256, 0, stream>>>(AO, Wb + 3 * 262144, (float*)d_out, bo);
}

// Round 8
// 131.064 us; speedup vs baseline: 1.3741x; 1.3741x over previous
//
#include <hip/hip_runtime.h>

// ---------------------------------------------------------------------------
// Attention block, faithful to reference quirks:
//  - raw reshape head split: per (b,h) Q/K/V are contiguous [2048,64] slabs
//  - softmax over QUERY axis: attn[q,k] = exp(s[q,k]) / sum_q exp(s[q,k])
// Algebra: Z[k] = sum_q exp(s); fold 1/Z into V (Vn = V/Z); out = exp(S)@Vn.
// k_colv emits Vn in FRAGMENT-LINEAR layout VF: 16B chunk per
// (tp,dt,wid,lane) = {Vn[d][kA..kA+3], Vn[d][kB..kB+3]} with d=dt*16+(lane&15),
// kA=tp*128+wid*16+(lane>>4)*4, kB=kA+64 — so k_attn's V loads are perfectly
// coalesced dwordx4 and the main loop needs NO LDS and NO barriers.
// Numerics: round-5-proven (__expf, bfpack, 0.125 Q scale).
// ---------------------------------------------------------------------------

typedef unsigned short ush;
typedef short s16v8 __attribute__((ext_vector_type(8)));
typedef float f32x4 __attribute__((ext_vector_type(4)));

#define BATCH_STRIDE 1048576   // T*D = 2048*512
#define HEAD_STRIDE  131072    // T*hd = 2048*64

__device__ __forceinline__ ush f2bf(float f) {
  unsigned int u = __builtin_bit_cast(unsigned int, f);
  u = (u + 0x7FFFu + ((u >> 16) & 1u)) >> 16;   // round-to-nearest-even
  return (ush)u;
}
__device__ __forceinline__ float bf2f(ush u) {
  return __builtin_bit_cast(float, (unsigned int)u << 16);
}
// fast pack two f32 -> 2xbf16 u32 (round-half-up; P is positive & well-scaled)
__device__ __forceinline__ unsigned int bfpack(float lo, float hi) {
  unsigned int ul = __builtin_bit_cast(unsigned int, lo) + 0x8000u;
  unsigned int uh = __builtin_bit_cast(unsigned int, hi) + 0x8000u;
  return (uh & 0xFFFF0000u) | (ul >> 16);
}

// swizzled LDS tile (8-chunk rows): 16B chunk at slot = row*8 + (ch ^ (row&7))
__device__ __forceinline__ s16v8 ldsfrag(const ush* base, int row, int ch) {
  return *(const s16v8*)(base + (((row) << 3) + ((ch) ^ ((row) & 7))) * 8);
}

__device__ __forceinline__ f32x4 mfma16(s16v8 a, s16v8 b, f32x4 c) {
  return __builtin_amdgcn_mfma_f32_16x16x32_bf16(a, b, c, 0, 0, 0);
}

__device__ __forceinline__ void gll16(const ush* g, ush* l) {
  __builtin_amdgcn_global_load_lds(
      (const __attribute__((address_space(1))) void*)g,
      (__attribute__((address_space(3))) void*)l, 16, 0, 0);
}

// ---------------------------------------------------------------------------
// f32 -> bf16 for X and the 4 weight matrices
// ---------------------------------------------------------------------------
__global__ __launch_bounds__(256) void k_convert(
    const float* __restrict__ X, const float* __restrict__ Wq,
    const float* __restrict__ Wk, const float* __restrict__ Wv,
    const float* __restrict__ Wo, ush* __restrict__ Xb, ush* __restrict__ Wb) {
  int id = blockIdx.x * 256 + threadIdx.x;
  const float* src;
  ush* dst;
  int idx;
  if (id < 1048576) {
    src = X; dst = Xb; idx = id;
  } else {
    int t = id - 1048576;
    int w = t >> 16;
    idx = t & 65535;
    src = (w == 0) ? Wq : (w == 1) ? Wk : (w == 2) ? Wv : Wo;
    dst = Wb + w * 262144;
  }
  float4 v = ((const float4*)src)[idx];
  ushort4 o;
  o.x = f2bf(v.x); o.y = f2bf(v.y); o.z = f2bf(v.z); o.w = f2bf(v.w);
  ((ushort4*)dst)[idx] = o;
}

// ---------------------------------------------------------------------------
// 2-phase dbuf GEMM, BM=128 BN=128 BK=64 (verified round 2)
// ---------------------------------------------------------------------------
__device__ __forceinline__ void stage_tile(
    const ush* __restrict__ A, const ush* __restrict__ W,
    ush* lds, int m0, int n0, int k0, int wid, int lane) {
#pragma unroll
  for (int i = 0; i < 4; i++) {
    int s = wid * 4 + i;
    int row = s * 8 + (lane >> 3);
    int ch = (lane & 7) ^ (lane >> 3);
    gll16(A + (size_t)(m0 + row) * 512 + k0 + ch * 8, lds + s * 512);
    gll16(W + (size_t)(n0 + row) * 512 + k0 + ch * 8, lds + 8192 + s * 512);
  }
}

template <int OUTMODE>
__device__ __forceinline__ void gemm2(
    const ush* __restrict__ A, const ush* __restrict__ W,
    ush* __restrict__ Obf, float* __restrict__ Ofp,
    const float* __restrict__ bias, int m0, int n0) {
  __shared__ __align__(16) ush SM[2][16384];
  const int tid = threadIdx.x, lane = tid & 63, wid = tid >> 6;
  const int l16 = lane & 15, lg = lane >> 4;
  const int wr = wid >> 1, wc = wid & 1;

  const f32x4 z4 = {0.f, 0.f, 0.f, 0.f};
  f32x4 acc[4][4];
#pragma unroll
  for (int i = 0; i < 4; i++)
#pragma unroll
    for (int j = 0; j < 4; j++) acc[i][j] = z4;

  stage_tile(A, W, &SM[0][0], m0, n0, 0, wid, lane);
  __syncthreads();
  int cur = 0;
#pragma unroll 1
  for (int t = 0; t < 8; t++) {
    if (t < 7) stage_tile(A, W, &SM[cur ^ 1][0], m0, n0, (t + 1) * 64, wid, lane);
    const ush* At = &SM[cur][0];
    const ush* Bt = &SM[cur][8192];
    s16v8 af[4][2], bf2[4][2];
#pragma unroll
    for (int ms = 0; ms < 4; ms++)
#pragma unroll
      for (int ks = 0; ks < 2; ks++)
        af[ms][ks] = ldsfrag(At, wr * 64 + ms * 16 + l16, ks * 4 + lg);
#pragma unroll
    for (int ns = 0; ns < 4; ns++)
#pragma unroll
      for (int ks = 0; ks < 2; ks++)
        bf2[ns][ks] = ldsfrag(Bt, wc * 64 + ns * 16 + l16, ks * 4 + lg);
#pragma unroll
    for (int ms = 0; ms < 4; ms++)
#pragma unroll
      for (int ns = 0; ns < 4; ns++)
#pragma unroll
        for (int ks = 0; ks < 2; ks++)
          acc[ms][ns] = mfma16(af[ms][ks], bf2[ns][ks], acc[ms][ns]);
    __syncthreads();
    cur ^= 1;
  }

  if (OUTMODE == 0) {
    const int gc0 = n0 + wc * 64;
    const float alpha = (gc0 < 512) ? 0.125f : 1.0f;
    ush* cw = &SM[0][0] + wid * 4096;
#pragma unroll
    for (int ms = 0; ms < 4; ms++)
#pragma unroll
      for (int ns = 0; ns < 4; ns++)
#pragma unroll
        for (int r = 0; r < 4; r++) {
          int row = ms * 16 + lg * 4 + r;
          int col = ns * 16 + l16;
          int sw = (((col >> 3) ^ (row & 7)) << 3) + (col & 7);
          cw[row * 64 + sw] = f2bf(acc[ms][ns][r] * alpha);
        }
    __syncthreads();
    const int z = gc0 >> 9, jl = gc0 & 511;
    ush* og = Obf + (size_t)z * 4194304 + (size_t)(m0 + wr * 64) * 512 + jl;
#pragma unroll
    for (int i = 0; i < 8; i++) {
      int row = i * 8 + (lane >> 3), ch = lane & 7;
      s16v8 v = ldsfrag(cw, row, ch);
      *(s16v8*)(og + (size_t)row * 512 + ch * 8) = v;
    }
  } else {
#pragma unroll
    for (int ms = 0; ms < 4; ms++)
#pragma unroll
      for (int ns = 0; ns < 4; ns++) {
        int gcol = n0 + wc * 64 + ns * 16 + l16;
#pragma unroll
        for (int r = 0; r < 4; r++) {
          int grow = m0 + wr * 64 + ms * 16 + lg * 4 + r;
          Ofp[(size_t)grow * 512 + gcol] = acc[ms][ns][r] + bias[gcol];
        }
      }
  }
}

__global__ __launch_bounds__(256) void k_gemm_qkv(
    const ush* __restrict__ Xb, const ush* __restrict__ Wb,
    ush* __restrict__ QKV) {
  gemm2<0>(Xb, Wb, QKV, nullptr, nullptr, blockIdx.x * 128, blockIdx.y * 128);
}

__global__ __launch_bounds__(256) void k_gemm_out(
    const ush* __restrict__ AO, const ush* __restrict__ Wob,
    float* __restrict__ out, const float* __restrict__ bias) {
  gemm2<1>(AO, Wob, nullptr, out, bias, blockIdx.x * 128, blockIdx.y * 128);
}

// ---------------------------------------------------------------------------
// k_colv: per (tp: 128 k-rows, bh): Z[k] = sum_q exp(s[q,k]) via swapped-QK
// (K rows as A-operand in regs; Q direct-global), then Vn = V/Z emitted in
// fragment-linear layout VF (see header comment).
// grid: 512 = 8 xcd x 4 bh x 16 tp.
// ---------------------------------------------------------------------------
__global__ __launch_bounds__(256) void k_colv(
    const ush* __restrict__ Qb, const ush* __restrict__ Kb,
    const ush* __restrict__ Vb, ush* __restrict__ VF) {
  const int wg = blockIdx.x;
  const int xcd = wg & 7, slot = wg >> 3;
  const int bh = xcd * 4 + (slot >> 4), tp = slot & 15;
  const int b = bh >> 3, h = bh & 7;
  const size_t base = (size_t)b * BATCH_STRIDE + h * HEAD_STRIDE;
  const ush* Qg = Qb + base;
  const ush* Kg = Kb + base + tp * 8192;   // 128 k-rows x 64
  const ush* Vg = Vb + base + tp * 8192;
  ush* vfh = VF + base + tp * 8192;        // 1024 chunks x 8 shorts

  __shared__ float Zp[512];
  __shared__ float invZ[128];
  __shared__ __align__(16) ush L[128][72];

  const int tid = threadIdx.x, lane = tid & 63, wid = tid >> 6;
  const int l16 = lane & 15, lg = lane >> 4;

  // V tile (128x64) loaded early; latency hidden under the Z pass
  uint4 vr[4];
#pragma unroll
  for (int i = 0; i < 4; i++) {
    int cid = tid * 4 + i;
    vr[i] = *(const uint4*)(Vg + (size_t)(cid >> 3) * 64 + (cid & 7) * 8);
  }

  // K fragments (A-operand): rows kc*16+l16, hd = ks*32 + lg*8..+7
  s16v8 kf[8][2];
#pragma unroll
  for (int kc = 0; kc < 8; kc++)
#pragma unroll
    for (int ks = 0; ks < 2; ks++)
      kf[kc][ks] = *(const s16v8*)(Kg + (size_t)(kc * 16 + l16) * 64 + ks * 32 + lg * 8);

  const f32x4 z4 = {0.f, 0.f, 0.f, 0.f};
  f32x4 zacc[8];
#pragma unroll
  for (int kc = 0; kc < 8; kc++) zacc[kc] = z4;

#pragma unroll 1
  for (int t = 0; t < 8; t++) {
    size_t q0 = (size_t)(t * 4 + wid) * 64;
#pragma unroll
    for (int ms = 0; ms < 4; ms++) {
      const ush* qrow = Qg + (q0 + ms * 16 + l16) * 64;
      s16v8 qf0 = *(const s16v8*)(qrow + lg * 8);
      s16v8 qf1 = *(const s16v8*)(qrow + 32 + lg * 8);
#pragma unroll
      for (int kc = 0; kc < 8; kc++) {
        f32x4 s = mfma16(kf[kc][0], qf0, z4);
        s = mfma16(kf[kc][1], qf1, s);
#pragma unroll
        for (int r = 0; r < 4; r++) zacc[kc][r] += __expf(s[r]);
      }
    }
  }

  // V tile into LDS [k][d] (padded rows) while reducing Z
#pragma unroll
  for (int i = 0; i < 4; i++) {
    int cid = tid * 4 + i;
    *(uint4*)(&L[cid >> 3][(cid & 7) * 8]) = vr[i];
  }

  // per-wave partial: sum over the wave's 512 q (l16 groups)
#pragma unroll
  for (int kc = 0; kc < 8; kc++)
#pragma unroll
    for (int r = 0; r < 4; r++) {
      float v = zacc[kc][r];
      v += __shfl_xor(v, 1); v += __shfl_xor(v, 2);
      v += __shfl_xor(v, 4); v += __shfl_xor(v, 8);
      if (l16 == 0) Zp[wid * 128 + kc * 16 + lg * 4 + r] = v;
    }
  __syncthreads();
  if (tid < 128)
    invZ[tid] = 1.0f / (Zp[tid] + Zp[128 + tid] + Zp[256 + tid] + Zp[384 + tid]);
  __syncthreads();

  // emit fragment-linear VF: chunk c -> (dt, wid_t, lane_t)
#pragma unroll
  for (int i = 0; i < 4; i++) {
    int c = tid * 4 + i;
    int dt = c >> 8, wid_t = (c >> 6) & 3, lane_t = c & 63;
    int d = dt * 16 + (lane_t & 15);
    int kA = wid_t * 16 + ((lane_t >> 4) << 2);
    ush tmp[8];
#pragma unroll
    for (int j = 0; j < 4; j++)
      tmp[j] = f2bf(bf2f(L[kA + j][d]) * invZ[kA + j]);
#pragma unroll
    for (int j = 0; j < 4; j++)
      tmp[4 + j] = f2bf(bf2f(L[kA + 64 + j][d]) * invZ[kA + 64 + j]);
    *(uint4*)(vfh + c * 8) = *(const uint4*)tmp;
  }
}

// ---------------------------------------------------------------------------
// k_attn: out[q,d] = sum_k exp(s[q,k]) * Vn[k,d]
// Block: 64 q rows; 4 waves each own a 16-k slice of each 64-k tile; two
// tiles paired per iter (128 k) to fill K=32 MFMA fragments.
// Swapped QK (A=K) => lane holds P[q=l16][k=lg*4+r]: exact A-frag layout.
// K direct from L2; Vn via fragment-linear VF (perfectly coalesced dwordx4).
// NO LDS / barriers in main loop; LDS only for epilogue reduction.
// ---------------------------------------------------------------------------
__global__ __launch_bounds__(256) void k_attn(
    const ush* __restrict__ Qb, const ush* __restrict__ Kb,
    const ush* __restrict__ VF, ush* __restrict__ AO) {
  const int wg = blockIdx.x;
  const int xcd = wg & 7, slot = wg >> 3;
  const int bh = xcd * 4 + (slot >> 5), qb = slot & 31;
  const int b = bh >> 3, h = bh & 7;
  const size_t base = (size_t)b * BATCH_STRIDE + h * HEAD_STRIDE;
  const ush* Qg = Qb + base + qb * 4096;   // 64 q rows x 64 dims
  const ush* Kg = Kb + base;
  const ush* vfh = VF + base;              // fragment-linear Vn
  ush* aog = AO + base + qb * 4096;

  __shared__ __align__(16) char smraw[32768];  // epilogue only: 2 x 16KB

  const int tid = threadIdx.x, lane = tid & 63, wid = tid >> 6;
  const int l16 = lane & 15, lg = lane >> 4;

  // Q fragments direct from global (held whole kernel)
  s16v8 qa[4][2];
#pragma unroll
  for (int ms = 0; ms < 4; ms++)
#pragma unroll
    for (int ks = 0; ks < 2; ks++)
      qa[ms][ks] = *(const s16v8*)(Qg + (size_t)(ms * 16 + l16) * 64 + ks * 32 + lg * 8);

  const f32x4 z4 = {0.f, 0.f, 0.f, 0.f};
  f32x4 oacc[4][4];
#pragma unroll
  for (int i = 0; i < 4; i++)
#pragma unroll
    for (int j = 0; j < 4; j++) oacc[i][j] = z4;

  const ush* krow = Kg + (size_t)(wid * 16 + l16) * 64;
  const ush* vrow = vfh + (size_t)(wid * 64 + lane) * 8;

#pragma unroll 2
  for (int tp = 0; tp < 16; tp++) {
    // K fragments for both tiles of the pair (direct global, L2)
    const ush* kr = krow + (size_t)tp * 8192;
    s16v8 kf0[2], kf1[2];
    kf0[0] = *(const s16v8*)(kr + lg * 8);
    kf0[1] = *(const s16v8*)(kr + 32 + lg * 8);
    kf1[0] = *(const s16v8*)(kr + 4096 + lg * 8);
    kf1[1] = *(const s16v8*)(kr + 4096 + 32 + lg * 8);

    // Vn B-fragments: fully coalesced 16B per lane
    uint4 vbu[4];
#pragma unroll
    for (int dt = 0; dt < 4; dt++)
      vbu[dt] = *(const uint4*)(vrow + (size_t)(tp * 16 + dt * 4) * 512);

#pragma unroll
    for (int ms = 0; ms < 4; ms++) {
      f32x4 sA = mfma16(kf0[0], qa[ms][0], z4);
      sA = mfma16(kf0[1], qa[ms][1], sA);
      f32x4 sB = mfma16(kf1[0], qa[ms][0], z4);
      sB = mfma16(kf1[1], qa[ms][1], sB);
      uint4 pu;
      pu.x = bfpack(__expf(sA[0]), __expf(sA[1]));
      pu.y = bfpack(__expf(sA[2]), __expf(sA[3]));
      pu.z = bfpack(__expf(sB[0]), __expf(sB[1]));
      pu.w = bfpack(__expf(sB[2]), __expf(sB[3]));
      s16v8 pa = __builtin_bit_cast(s16v8, pu);
#pragma unroll
      for (int dt = 0; dt < 4; dt++)
        oacc[ms][dt] = mfma16(pa, __builtin_bit_cast(s16v8, vbu[dt]), oacc[ms][dt]);
    }
  }

  // ---- cross-wave k-slice reduction: slot-major, conflict-free ----
  float* red = (float*)smraw;
  if (wid >= 2) {
    float* rg = red + (wid - 2) * 4096;
#pragma unroll
    for (int ms = 0; ms < 4; ms++)
#pragma unroll
      for (int dt = 0; dt < 4; dt++)
        *(f32x4*)(rg + (ms * 4 + dt) * 256 + lane * 4) = oacc[ms][dt];
  }
  __syncthreads();
  if (wid < 2) {
    float* rg = red + wid * 4096;
#pragma unroll
    for (int ms = 0; ms < 4; ms++)
#pragma unroll
      for (int dt = 0; dt < 4; dt++)
        oacc[ms][dt] += *(const f32x4*)(rg + (ms * 4 + dt) * 256 + lane * 4);
  }
  __syncthreads();
  if (wid == 1) {
#pragma unroll
    for (int ms = 0; ms < 4; ms++)
#pragma unroll
      for (int dt = 0; dt < 4; dt++)
        *(f32x4*)(red + (ms * 4 + dt) * 256 + lane * 4) = oacc[ms][dt];
  }
  __syncthreads();
  if (wid == 0) {
#pragma unroll
    for (int ms = 0; ms < 4; ms++)
#pragma unroll
      for (int dt = 0; dt < 4; dt++)
        oacc[ms][dt] += *(const f32x4*)(red + (ms * 4 + dt) * 256 + lane * 4);
  }
  __syncthreads();   // all reads done before out-tile overwrites region 0
  ush* ot = (ush*)smraw;   // 64x64 bf16 out tile
  if (wid == 0) {
#pragma unroll
    for (int ms = 0; ms < 4; ms++)
#pragma unroll
      for (int dt = 0; dt < 4; dt++)
#pragma unroll
        for (int r = 0; r < 4; r++)
          ot[(ms * 16 + lg * 4 + r) * 64 + dt * 16 + l16] = f2bf(oacc[ms][dt][r]);
  }
  __syncthreads();
#pragma unroll
  for (int rd = 0; rd < 2; rd++) {
    int id = rd * 256 + tid;
    *(s16v8*)(aog + id * 8) = *(const s16v8*)(ot + id * 8);
  }
}

// ---------------------------------------------------------------------------
extern "C" void kernel_launch(void* const* d_in, const int* in_sizes, int n_in,
                              void* d_out, int out_size, void* d_ws, size_t ws_size,
                              hipStream_t stream) {
  const float* X  = (const float*)d_in[0];
  const float* Wq = (const float*)d_in[1];
  const float* Wk = (const float*)d_in[2];
  const float* Wv = (const float*)d_in[3];
  const float* Wo = (const float*)d_in[4];
  const float* bo = (const float*)d_in[5];

  ush* Qb  = (ush*)d_ws;          // QKV contiguous: 3 x 4M bf16
  ush* Kb  = Qb + 4194304;
  ush* Vb  = Kb + 4194304;
  ush* VF  = Vb + 4194304;        // fragment-linear Vn per head
  ush* AO  = VF + 4194304;
  ush* Xb  = AO + 4194304;
  ush* Wb  = Xb + 4194304;        // 4 x 262144 (Wq,Wk,Wv,Wo)

  k_convert<<<5120, 256, 0, stream>>>(X, Wq, Wk, Wv, Wo, Xb, Wb);
  k_gemm_qkv<<<dim3(64, 12), 256, 0, stream>>>(Xb, Wb, Qb);
  k_colv<<<512, 256, 0, stream>>>(Qb, Kb, Vb, VF);
  k_attn<<<1024, 256, 0, stream>>>(Qb, Kb, VF, AO);
  k_gemm_out<<<dim3(64, 4), 256, 0, stream>>>(AO, Wb + 3 * 262144, (float*)d_out, bo);
}

// Round 9
// 126.699 us; speedup vs baseline: 1.4214x; 1.0344x over previous
//
#include <hip/hip_runtime.h>

// ---------------------------------------------------------------------------
// Attention block, faithful to reference quirks:
//  - raw reshape head split: per (b,h) Q/K/V are contiguous [2048,64] slabs
//  - softmax over QUERY axis: attn[q,k] = exp(s[q,k]) / sum_q exp(s[q,k])
// Algebra: Z[k] = sum_q exp(s); fold 1/Z into V (Vn = V/Z); out = exp(S)@Vn.
// Q carries 0.125*log2(e) so exp is a single v_exp_f32 (2^x); base change
// cancels exactly in the softmax ratio (round-5's __expf did x*log2e + 2^x
// at runtime — identical numerics class, one less VALU op).
// k_colv emits Vn in FRAGMENT-LINEAR layout VF: 16B chunk per
// (tp,dt,wid,lane) so k_attn's V loads are perfectly coalesced dwordx4;
// main loop has NO LDS and NO barriers. bfpack (not cvt_pk asm — round-6
// failure attributed to it) for P->bf16.
// ---------------------------------------------------------------------------

typedef unsigned short ush;
typedef short s16v8 __attribute__((ext_vector_type(8)));
typedef float f32x4 __attribute__((ext_vector_type(4)));

#define BATCH_STRIDE 1048576   // T*D = 2048*512
#define HEAD_STRIDE  131072    // T*hd = 2048*64
#define ALPHA_Q 0.18033688011112042f   // 0.125 * log2(e)

__device__ __forceinline__ ush f2bf(float f) {
  unsigned int u = __builtin_bit_cast(unsigned int, f);
  u = (u + 0x7FFFu + ((u >> 16) & 1u)) >> 16;   // round-to-nearest-even
  return (ush)u;
}
__device__ __forceinline__ float bf2f(ush u) {
  return __builtin_bit_cast(float, (unsigned int)u << 16);
}
// fast pack two f32 -> 2xbf16 u32 (round-half-up; P is positive & well-scaled)
__device__ __forceinline__ unsigned int bfpack(float lo, float hi) {
  unsigned int ul = __builtin_bit_cast(unsigned int, lo) + 0x8000u;
  unsigned int uh = __builtin_bit_cast(unsigned int, hi) + 0x8000u;
  return (uh & 0xFFFF0000u) | (ul >> 16);
}
__device__ __forceinline__ float fexp2(float x) {
#if __has_builtin(__builtin_amdgcn_exp2f)
  return __builtin_amdgcn_exp2f(x);
#else
  return exp2f(x);
#endif
}

// swizzled LDS tile (8-chunk rows): 16B chunk at slot = row*8 + (ch ^ (row&7))
__device__ __forceinline__ s16v8 ldsfrag(const ush* base, int row, int ch) {
  return *(const s16v8*)(base + (((row) << 3) + ((ch) ^ ((row) & 7))) * 8);
}

__device__ __forceinline__ f32x4 mfma16(s16v8 a, s16v8 b, f32x4 c) {
  return __builtin_amdgcn_mfma_f32_16x16x32_bf16(a, b, c, 0, 0, 0);
}

__device__ __forceinline__ void gll16(const ush* g, ush* l) {
  __builtin_amdgcn_global_load_lds(
      (const __attribute__((address_space(1))) void*)g,
      (__attribute__((address_space(3))) void*)l, 16, 0, 0);
}

// ---------------------------------------------------------------------------
// f32 -> bf16 for X and the 4 weight matrices
// ---------------------------------------------------------------------------
__global__ __launch_bounds__(256) void k_convert(
    const float* __restrict__ X, const float* __restrict__ Wq,
    const float* __restrict__ Wk, const float* __restrict__ Wv,
    const float* __restrict__ Wo, ush* __restrict__ Xb, ush* __restrict__ Wb) {
  int id = blockIdx.x * 256 + threadIdx.x;
  const float* src;
  ush* dst;
  int idx;
  if (id < 1048576) {
    src = X; dst = Xb; idx = id;
  } else {
    int t = id - 1048576;
    int w = t >> 16;
    idx = t & 65535;
    src = (w == 0) ? Wq : (w == 1) ? Wk : (w == 2) ? Wv : Wo;
    dst = Wb + w * 262144;
  }
  float4 v = ((const float4*)src)[idx];
  ushort4 o;
  o.x = f2bf(v.x); o.y = f2bf(v.y); o.z = f2bf(v.z); o.w = f2bf(v.w);
  ((ushort4*)dst)[idx] = o;
}

// ---------------------------------------------------------------------------
// 2-phase dbuf GEMM, BM=128 BN=128 BK=64 (verified round 2)
// ---------------------------------------------------------------------------
__device__ __forceinline__ void stage_tile(
    const ush* __restrict__ A, const ush* __restrict__ W,
    ush* lds, int m0, int n0, int k0, int wid, int lane) {
#pragma unroll
  for (int i = 0; i < 4; i++) {
    int s = wid * 4 + i;
    int row = s * 8 + (lane >> 3);
    int ch = (lane & 7) ^ (lane >> 3);
    gll16(A + (size_t)(m0 + row) * 512 + k0 + ch * 8, lds + s * 512);
    gll16(W + (size_t)(n0 + row) * 512 + k0 + ch * 8, lds + 8192 + s * 512);
  }
}

template <int OUTMODE>
__device__ __forceinline__ void gemm2(
    const ush* __restrict__ A, const ush* __restrict__ W,
    ush* __restrict__ Obf, float* __restrict__ Ofp,
    const float* __restrict__ bias, int m0, int n0) {
  __shared__ __align__(16) ush SM[2][16384];
  const int tid = threadIdx.x, lane = tid & 63, wid = tid >> 6;
  const int l16 = lane & 15, lg = lane >> 4;
  const int wr = wid >> 1, wc = wid & 1;

  const f32x4 z4 = {0.f, 0.f, 0.f, 0.f};
  f32x4 acc[4][4];
#pragma unroll
  for (int i = 0; i < 4; i++)
#pragma unroll
    for (int j = 0; j < 4; j++) acc[i][j] = z4;

  stage_tile(A, W, &SM[0][0], m0, n0, 0, wid, lane);
  __syncthreads();
  int cur = 0;
#pragma unroll 1
  for (int t = 0; t < 8; t++) {
    if (t < 7) stage_tile(A, W, &SM[cur ^ 1][0], m0, n0, (t + 1) * 64, wid, lane);
    const ush* At = &SM[cur][0];
    const ush* Bt = &SM[cur][8192];
    s16v8 af[4][2], bf2[4][2];
#pragma unroll
    for (int ms = 0; ms < 4; ms++)
#pragma unroll
      for (int ks = 0; ks < 2; ks++)
        af[ms][ks] = ldsfrag(At, wr * 64 + ms * 16 + l16, ks * 4 + lg);
#pragma unroll
    for (int ns = 0; ns < 4; ns++)
#pragma unroll
      for (int ks = 0; ks < 2; ks++)
        bf2[ns][ks] = ldsfrag(Bt, wc * 64 + ns * 16 + l16, ks * 4 + lg);
#pragma unroll
    for (int ms = 0; ms < 4; ms++)
#pragma unroll
      for (int ns = 0; ns < 4; ns++)
#pragma unroll
        for (int ks = 0; ks < 2; ks++)
          acc[ms][ns] = mfma16(af[ms][ks], bf2[ns][ks], acc[ms][ns]);
    __syncthreads();
    cur ^= 1;
  }

  if (OUTMODE == 0) {
    const int gc0 = n0 + wc * 64;
    const float alpha = (gc0 < 512) ? ALPHA_Q : 1.0f;  // Q carries 1/8*log2e
    ush* cw = &SM[0][0] + wid * 4096;
#pragma unroll
    for (int ms = 0; ms < 4; ms++)
#pragma unroll
      for (int ns = 0; ns < 4; ns++)
#pragma unroll
        for (int r = 0; r < 4; r++) {
          int row = ms * 16 + lg * 4 + r;
          int col = ns * 16 + l16;
          int sw = (((col >> 3) ^ (row & 7)) << 3) + (col & 7);
          cw[row * 64 + sw] = f2bf(acc[ms][ns][r] * alpha);
        }
    __syncthreads();
    const int z = gc0 >> 9, jl = gc0 & 511;
    ush* og = Obf + (size_t)z * 4194304 + (size_t)(m0 + wr * 64) * 512 + jl;
#pragma unroll
    for (int i = 0; i < 8; i++) {
      int row = i * 8 + (lane >> 3), ch = lane & 7;
      s16v8 v = ldsfrag(cw, row, ch);
      *(s16v8*)(og + (size_t)row * 512 + ch * 8) = v;
    }
  } else {
#pragma unroll
    for (int ms = 0; ms < 4; ms++)
#pragma unroll
      for (int ns = 0; ns < 4; ns++) {
        int gcol = n0 + wc * 64 + ns * 16 + l16;
#pragma unroll
        for (int r = 0; r < 4; r++) {
          int grow = m0 + wr * 64 + ms * 16 + lg * 4 + r;
          Ofp[(size_t)grow * 512 + gcol] = acc[ms][ns][r] + bias[gcol];
        }
      }
  }
}

__global__ __launch_bounds__(256) void k_gemm_qkv(
    const ush* __restrict__ Xb, const ush* __restrict__ Wb,
    ush* __restrict__ QKV) {
  gemm2<0>(Xb, Wb, QKV, nullptr, nullptr, blockIdx.x * 128, blockIdx.y * 128);
}

__global__ __launch_bounds__(256) void k_gemm_out(
    const ush* __restrict__ AO, const ush* __restrict__ Wob,
    float* __restrict__ out, const float* __restrict__ bias) {
  gemm2<1>(AO, Wob, nullptr, out, bias, blockIdx.x * 128, blockIdx.y * 128);
}

// ---------------------------------------------------------------------------
// k_colv: per (tp: 128 k-rows, bh): Z[k] = sum_q 2^(s'[q,k]) via swapped-QK
// (K rows as A-operand in regs; Q direct-global), then Vn = V/Z emitted in
// fragment-linear layout VF.  grid: 512 = 8 xcd x 4 bh x 16 tp.
// ---------------------------------------------------------------------------
__global__ __launch_bounds__(256) void k_colv(
    const ush* __restrict__ Qb, const ush* __restrict__ Kb,
    const ush* __restrict__ Vb, ush* __restrict__ VF) {
  const int wg = blockIdx.x;
  const int xcd = wg & 7, slot = wg >> 3;
  const int bh = xcd * 4 + (slot >> 4), tp = slot & 15;
  const int b = bh >> 3, h = bh & 7;
  const size_t base = (size_t)b * BATCH_STRIDE + h * HEAD_STRIDE;
  const ush* Qg = Qb + base;
  const ush* Kg = Kb + base + tp * 8192;   // 128 k-rows x 64
  const ush* Vg = Vb + base + tp * 8192;
  ush* vfh = VF + base + tp * 8192;        // 1024 chunks x 8 shorts

  __shared__ float Zp[512];
  __shared__ float invZ[128];
  __shared__ __align__(16) ush L[128][72];

  const int tid = threadIdx.x, lane = tid & 63, wid = tid >> 6;
  const int l16 = lane & 15, lg = lane >> 4;

  // V tile (128x64) loaded early; latency hidden under the Z pass
  uint4 vr[4];
#pragma unroll
  for (int i = 0; i < 4; i++) {
    int cid = tid * 4 + i;
    vr[i] = *(const uint4*)(Vg + (size_t)(cid >> 3) * 64 + (cid & 7) * 8);
  }

  // K fragments (A-operand): rows kc*16+l16, hd = ks*32 + lg*8..+7
  s16v8 kf[8][2];
#pragma unroll
  for (int kc = 0; kc < 8; kc++)
#pragma unroll
    for (int ks = 0; ks < 2; ks++)
      kf[kc][ks] = *(const s16v8*)(Kg + (size_t)(kc * 16 + l16) * 64 + ks * 32 + lg * 8);

  const f32x4 z4 = {0.f, 0.f, 0.f, 0.f};
  f32x4 zacc[8];
#pragma unroll
  for (int kc = 0; kc < 8; kc++) zacc[kc] = z4;

#pragma unroll 1
  for (int t = 0; t < 8; t++) {
    size_t q0 = (size_t)(t * 4 + wid) * 64;
#pragma unroll
    for (int ms = 0; ms < 4; ms++) {
      const ush* qrow = Qg + (q0 + ms * 16 + l16) * 64;
      s16v8 qf0 = *(const s16v8*)(qrow + lg * 8);
      s16v8 qf1 = *(const s16v8*)(qrow + 32 + lg * 8);
      __builtin_amdgcn_s_setprio(1);
#pragma unroll
      for (int kc = 0; kc < 8; kc++) {
        f32x4 s = mfma16(kf[kc][0], qf0, z4);
        s = mfma16(kf[kc][1], qf1, s);
#pragma unroll
        for (int r = 0; r < 4; r++) zacc[kc][r] += fexp2(s[r]);
      }
      __builtin_amdgcn_s_setprio(0);
    }
  }

  // V tile into LDS [k][d] (padded rows) while reducing Z
#pragma unroll
  for (int i = 0; i < 4; i++) {
    int cid = tid * 4 + i;
    *(uint4*)(&L[cid >> 3][(cid & 7) * 8]) = vr[i];
  }

  // per-wave partial: sum over the wave's 512 q (l16 groups)
#pragma unroll
  for (int kc = 0; kc < 8; kc++)
#pragma unroll
    for (int r = 0; r < 4; r++) {
      float v = zacc[kc][r];
      v += __shfl_xor(v, 1); v += __shfl_xor(v, 2);
      v += __shfl_xor(v, 4); v += __shfl_xor(v, 8);
      if (l16 == 0) Zp[wid * 128 + kc * 16 + lg * 4 + r] = v;
    }
  __syncthreads();
  if (tid < 128)
    invZ[tid] = 1.0f / (Zp[tid] + Zp[128 + tid] + Zp[256 + tid] + Zp[384 + tid]);
  __syncthreads();

  // emit fragment-linear VF: chunk c -> (dt, wid_t, lane_t)
#pragma unroll
  for (int i = 0; i < 4; i++) {
    int c = tid * 4 + i;
    int dt = c >> 8, wid_t = (c >> 6) & 3, lane_t = c & 63;
    int d = dt * 16 + (lane_t & 15);
    int kA = wid_t * 16 + ((lane_t >> 4) << 2);
    ush tmp[8];
#pragma unroll
    for (int j = 0; j < 4; j++)
      tmp[j] = f2bf(bf2f(L[kA + j][d]) * invZ[kA + j]);
#pragma unroll
    for (int j = 0; j < 4; j++)
      tmp[4 + j] = f2bf(bf2f(L[kA + 64 + j][d]) * invZ[kA + 64 + j]);
    *(uint4*)(vfh + c * 8) = *(const uint4*)tmp;
  }
}

// ---------------------------------------------------------------------------
// k_attn: out[q,d] = sum_k 2^(s'[q,k]) * Vn[k,d]
// Block: 64 q rows; 4 waves each own a 16-k slice of each 64-k tile; two
// tiles paired per iter (128 k) to fill K=32 MFMA fragments.
// Swapped QK (A=K) => lane holds P[q=l16][k=lg*4+r]: exact A-frag layout.
// K direct from L2; Vn via fragment-linear VF (coalesced dwordx4).
// NO LDS / barriers in main loop; LDS only for epilogue reduction.
// unroll 4 for cross-iteration ILP; setprio(1) around compute cluster (T5).
// ---------------------------------------------------------------------------
__global__ __launch_bounds__(256) void k_attn(
    const ush* __restrict__ Qb, const ush* __restrict__ Kb,
    const ush* __restrict__ VF, ush* __restrict__ AO) {
  const int wg = blockIdx.x;
  const int xcd = wg & 7, slot = wg >> 3;
  const int bh = xcd * 4 + (slot >> 5), qb = slot & 31;
  const int b = bh >> 3, h = bh & 7;
  const size_t base = (size_t)b * BATCH_STRIDE + h * HEAD_STRIDE;
  const ush* Qg = Qb + base + qb * 4096;   // 64 q rows x 64 dims
  const ush* Kg = Kb + base;
  const ush* vfh = VF + base;              // fragment-linear Vn
  ush* aog = AO + base + qb * 4096;

  __shared__ __align__(16) char smraw[32768];  // epilogue only: 2 x 16KB

  const int tid = threadIdx.x, lane = tid & 63, wid = tid >> 6;
  const int l16 = lane & 15, lg = lane >> 4;

  // Q fragments direct from global (held whole kernel)
  s16v8 qa[4][2];
#pragma unroll
  for (int ms = 0; ms < 4; ms++)
#pragma unroll
    for (int ks = 0; ks < 2; ks++)
      qa[ms][ks] = *(const s16v8*)(Qg + (size_t)(ms * 16 + l16) * 64 + ks * 32 + lg * 8);

  const f32x4 z4 = {0.f, 0.f, 0.f, 0.f};
  f32x4 oacc[4][4];
#pragma unroll
  for (int i = 0; i < 4; i++)
#pragma unroll
    for (int j = 0; j < 4; j++) oacc[i][j] = z4;

  const ush* krow = Kg + (size_t)(wid * 16 + l16) * 64;
  const ush* vrow = vfh + (size_t)(wid * 64 + lane) * 8;

#pragma unroll 4
  for (int tp = 0; tp < 16; tp++) {
    // K fragments for both tiles of the pair (direct global, L2)
    const ush* kr = krow + (size_t)tp * 8192;
    s16v8 kf0[2], kf1[2];
    kf0[0] = *(const s16v8*)(kr + lg * 8);
    kf0[1] = *(const s16v8*)(kr + 32 + lg * 8);
    kf1[0] = *(const s16v8*)(kr + 4096 + lg * 8);
    kf1[1] = *(const s16v8*)(kr + 4096 + 32 + lg * 8);

    // Vn B-fragments: fully coalesced 16B per lane
    uint4 vbu[4];
#pragma unroll
    for (int dt = 0; dt < 4; dt++)
      vbu[dt] = *(const uint4*)(vrow + (size_t)(tp * 16 + dt * 4) * 512);

    __builtin_amdgcn_s_setprio(1);
#pragma unroll
    for (int ms = 0; ms < 4; ms++) {
      f32x4 sA = mfma16(kf0[0], qa[ms][0], z4);
      sA = mfma16(kf0[1], qa[ms][1], sA);
      f32x4 sB = mfma16(kf1[0], qa[ms][0], z4);
      sB = mfma16(kf1[1], qa[ms][1], sB);
      uint4 pu;
      pu.x = bfpack(fexp2(sA[0]), fexp2(sA[1]));
      pu.y = bfpack(fexp2(sA[2]), fexp2(sA[3]));
      pu.z = bfpack(fexp2(sB[0]), fexp2(sB[1]));
      pu.w = bfpack(fexp2(sB[2]), fexp2(sB[3]));
      s16v8 pa = __builtin_bit_cast(s16v8, pu);
#pragma unroll
      for (int dt = 0; dt < 4; dt++)
        oacc[ms][dt] = mfma16(pa, __builtin_bit_cast(s16v8, vbu[dt]), oacc[ms][dt]);
    }
    __builtin_amdgcn_s_setprio(0);
  }

  // ---- cross-wave k-slice reduction: slot-major, conflict-free ----
  float* red = (float*)smraw;
  if (wid >= 2) {
    float* rg = red + (wid - 2) * 4096;
#pragma unroll
    for (int ms = 0; ms < 4; ms++)
#pragma unroll
      for (int dt = 0; dt < 4; dt++)
        *(f32x4*)(rg + (ms * 4 + dt) * 256 + lane * 4) = oacc[ms][dt];
  }
  __syncthreads();
  if (wid < 2) {
    float* rg = red + wid * 4096;
#pragma unroll
    for (int ms = 0; ms < 4; ms++)
#pragma unroll
      for (int dt = 0; dt < 4; dt++)
        oacc[ms][dt] += *(const f32x4*)(rg + (ms * 4 + dt) * 256 + lane * 4);
  }
  __syncthreads();
  if (wid == 1) {
#pragma unroll
    for (int ms = 0; ms < 4; ms++)
#pragma unroll
      for (int dt = 0; dt < 4; dt++)
        *(f32x4*)(red + (ms * 4 + dt) * 256 + lane * 4) = oacc[ms][dt];
  }
  __syncthreads();
  if (wid == 0) {
#pragma unroll
    for (int ms = 0; ms < 4; ms++)
#pragma unroll
      for (int dt = 0; dt < 4; dt++)
        oacc[ms][dt] += *(const f32x4*)(red + (ms * 4 + dt) * 256 + lane * 4);
  }
  __syncthreads();   // all reads done before out-tile overwrites region 0
  ush* ot = (ush*)smraw;   // 64x64 bf16 out tile
  if (wid == 0) {
#pragma unroll
    for (int ms = 0; ms < 4; ms++)
#pragma unroll
      for (int dt = 0; dt < 4; dt++)
#pragma unroll
        for (int r = 0; r < 4; r++)
          ot[(ms * 16 + lg * 4 + r) * 64 + dt * 16 + l16] = f2bf(oacc[ms][dt][r]);
  }
  __syncthreads();
#pragma unroll
  for (int rd = 0; rd < 2; rd++) {
    int id = rd * 256 + tid;
    *(s16v8*)(aog + id * 8) = *(const s16v8*)(ot + id * 8);
  }
}

// ---------------------------------------------------------------------------
extern "C" void kernel_launch(void* const* d_in, const int* in_sizes, int n_in,
                              void* d_out, int out_size, void* d_ws, size_t ws_size,
                              hipStream_t stream) {
  const float* X  = (const float*)d_in[0];
  const float* Wq = (const float*)d_in[1];
  const float* Wk = (const float*)d_in[2];
  const float* Wv = (const float*)d_in[3];
  const float* Wo = (const float*)d_in[4];
  const float* bo = (const float*)d_in[5];

  ush* Qb  = (ush*)d_ws;          // QKV contiguous: 3 x 4M bf16
  ush* Kb  = Qb + 4194304;
  ush* Vb  = Kb + 4194304;
  ush* VF  = Vb + 4194304;        // fragment-linear Vn per head
  ush* AO  = VF + 4194304;
  ush* Xb  = AO + 4194304;
  ush* Wb  = Xb + 4194304;        // 4 x 262144 (Wq,Wk,Wv,Wo)

  k_convert<<<5120, 256, 0, stream>>>(X, Wq, Wk, Wv, Wo, Xb, Wb);
  k_gemm_qkv<<<dim3(64, 12), 256, 0, stream>>>(Xb, Wb, Qb);
  k_colv<<<512, 256, 0, stream>>>(Qb, Kb, Vb, VF);
  k_attn<<<1024, 256, 0, stream>>>(Qb, Kb, VF, AO);
  k_gemm_out<<<dim3(64, 4), 256, 0, stream>>>(AO, Wb + 3 * 262144, (float*)d_out, bo);
}